// Round 7
// baseline (112.118 us; speedup 1.0000x reference)
//
#include <hip/hip_runtime.h>
#include <math.h>

#define NQ 512
#define NC 8000
#define DNUM 6
#define NBINS 50
#define DCAT 20
#define DENC 26      // DNUM + DCAT
#define DOUT 10
#define CHUNK 1000
#define NCHUNK 8
#define QT 16        // queries per block (R1's measured-spill-free shape)

// ---------- encode ----------
// G_f(v) = sum_j ceil((v - u_fj*delta_fj)/delta_fj). Each per-bin map is
// fp-monotone in v (sub, div-by-positive, ceil), so all 50 bin diffs for a
// feature share sign => sum_j |bin_j(x)-bin_j(c)| == |G_f(x)-G_f(c)| exactly
// (integer-valued floats, sums << 2^24). 320-dim L1 -> 26-dim L1.
__global__ void encode(const float* __restrict__ c_num, const float* __restrict__ c_cat,
                       const float* __restrict__ x_num, const float* __restrict__ x_cat,
                       const float* __restrict__ delta, const float* __restrict__ u,
                       float* __restrict__ cEnc, float* __restrict__ qEnc,
                       float* __restrict__ g_logits) {
    int i = blockIdx.x * 256 + threadIdx.x;
    const int nA = (NC + NQ) * DNUM;          // 51072
    const int nB = (NC + NQ) * DCAT;          // 170240
    if (i < nA) {
        int f = i % DNUM, p = i / DNUM;
        bool is_c = p < NC;
        int idx = is_c ? p : p - NC;
        float v = (is_c ? c_num : x_num)[idx * DNUM + f];
        float g = 0.f;
        for (int j = 0; j < NBINS; ++j) {
            // exact reference op order: scaled_u = u*delta; ceil((v - scaled_u)/delta)
            float dl = delta[f * NBINS + j];
            float sc = u[f * NBINS + j] * dl;
            g += ceilf((v - sc) / dl);
        }
        if (is_c) cEnc[f * NC + idx] = g;
        else      qEnc[f * NQ + idx] = g;
    } else if (i < nA + nB) {
        int i2 = i - nA;
        int k = i2 % DCAT, p = i2 / DCAT;
        bool is_c = p < NC;
        int idx = is_c ? p : p - NC;
        float v = (is_c ? c_cat : x_cat)[idx * DCAT + k];
        if (is_c) cEnc[(DNUM + k) * NC + idx] = v;
        else      qEnc[(DNUM + k) * NQ + idx] = v;
    } else {
        int i3 = i - nA - nB;
        if (i3 < NQ * DOUT) g_logits[i3] = 0.f;
    }
}

// ---------- main: exact R1 structure (measured: VGPR=52, VALUBusy=54%, no
// spill), dimension count 320 -> 26. Block = (16-query tile, one chunk),
// 512 threads, 500 active x 2 candidates (float2). LDS-staged q-tile,
// acc float2[16] = 32 VGPRs of live state.
__global__ __launch_bounds__(512) void nca_main(
    const float* __restrict__ cEnc, const float* __restrict__ qEnc,
    const int* __restrict__ cy,
    float* __restrict__ g_logits, float* __restrict__ parts) {
    __shared__ float xs[DENC * QT];           // 416 floats
    __shared__ float lds_logits[QT * DOUT];   // 160
    __shared__ float wred[QT * 8];
    __shared__ float m_sh[QT];

    const int tid = threadIdx.x;
    const int q0 = blockIdx.x * QT;
    const int chunk = blockIdx.y;

    for (int i = tid; i < DENC * QT; i += 512) {
        int d = i >> 4, q = i & (QT - 1);
        xs[i] = qEnc[d * NQ + q0 + q];
    }
    if (tid < QT * DOUT) lds_logits[tid] = 0.f;
    __syncthreads();

    const bool active = (tid < 500);           // 500 threads * 2 candidates = 1000
    const int cl = active ? (2 * tid) : 998;   // clamp inactive lanes to safe addr
    const float* cp = cEnc + chunk * CHUNK + cl;

    float2 acc[QT];
#pragma unroll
    for (int q = 0; q < QT; ++q) acc[q] = make_float2(0.f, 0.f);

#pragma unroll 2
    for (int d = 0; d < DENC; ++d) {
        float2 cv = *(const float2*)(cp + (size_t)d * NC);
        const float* xv = xs + d * QT;
#pragma unroll
        for (int q = 0; q < QT; ++q) {
            float xq = xv[q];
            acc[q].x += fabsf(cv.x - xq);
            acc[q].y += fabsf(cv.y - xq);
        }
    }

    // ---- logits: sum exp(-dist) per class via LDS atomics ----
    if (active) {
        int2 yv = *(const int2*)(cy + chunk * CHUNK + cl);
#pragma unroll
        for (int q = 0; q < QT; ++q) {
            atomicAdd(&lds_logits[q * DOUT + yv.x], __expf(-acc[q].x));
            atomicAdd(&lds_logits[q * DOUT + yv.y], __expf(-acc[q].y));
        }
    }

    const int lane = tid & 63, wave = tid >> 6;

    // ---- per-q chunk min(dist) ----
#pragma unroll
    for (int q = 0; q < QT; ++q) {
        float v = active ? fminf(acc[q].x, acc[q].y) : INFINITY;
#pragma unroll
        for (int m = 32; m >= 1; m >>= 1) v = fminf(v, __shfl_xor(v, m));
        if (lane == 0) wred[q * 8 + wave] = v;
    }
    __syncthreads();
    if (tid < QT) {
        float m = wred[tid * 8];
#pragma unroll
        for (int w = 1; w < 8; ++w) m = fminf(m, wred[tid * 8 + w]);
        m_sh[tid] = m;
    }
    __syncthreads();

    // ---- stable sum: s = sum exp(m - dist) over the chunk ----
#pragma unroll
    for (int q = 0; q < QT; ++q) {
        float m = m_sh[q];
        float s = active ? (__expf(m - acc[q].x) + __expf(m - acc[q].y)) : 0.f;
#pragma unroll
        for (int mm = 32; mm >= 1; mm >>= 1) s += __shfl_xor(s, mm);
        if (lane == 0) wred[q * 8 + wave] = s;
    }
    __syncthreads();
    if (tid < QT) {
        float s = 0.f;
#pragma unroll
        for (int w = 0; w < 8; ++w) s += wred[tid * 8 + w];
        // per-(q, chunk) partial: lse_chunk = log(s) - m
        *(float2*)(parts + 2 * ((size_t)(q0 + tid) * NCHUNK + chunk)) =
            make_float2(m_sh[tid], s);
    }
    __syncthreads();
    if (tid < QT * DOUT)
        atomicAdd(&g_logits[q0 * DOUT + tid], lds_logits[tid]);
}

// ---------- finalize ----------
__global__ void finalize(const float* __restrict__ g_logits, const float* __restrict__ parts,
                         float* __restrict__ out) {
    int q = blockIdx.x * 256 + threadIdx.x;
    if (q >= NQ) return;
    float lse = 0.f;
#pragma unroll
    for (int ch = 0; ch < NCHUNK; ++ch) {
        float2 p = *(const float2*)(parts + 2 * ((size_t)q * NCHUNK + ch));
        lse += logf(p.y) - p.x;          // log(sum exp(m-d)) - m
    }
#pragma unroll
    for (int k = 0; k < DOUT; ++k)
        out[q * DOUT + k] = logf(g_logits[q * DOUT + k] + 1e-8f) - lse;
}

extern "C" void kernel_launch(void* const* d_in, const int* in_sizes, int n_in,
                              void* d_out, int out_size, void* d_ws, size_t ws_size,
                              hipStream_t stream) {
    const float* x_num = (const float*)d_in[0];
    const float* x_cat = (const float*)d_in[1];
    const float* c_num = (const float*)d_in[2];
    const float* c_cat = (const float*)d_in[3];
    const int*   c_y   = (const int*)d_in[4];
    const float* delta = (const float*)d_in[5];
    const float* u     = (const float*)d_in[6];

    float* ws = (float*)d_ws;
    float* cEnc = ws;                             // 26*8000 = 208,000 floats
    float* qEnc = cEnc + (size_t)DENC * NC;       // 26*512  = 13,312
    float* g_logits = qEnc + (size_t)DENC * NQ;   // 5,120
    float* parts = g_logits + NQ * DOUT;          // 512*8*2 = 8,192

    const int total = (NC + NQ) * DENC + NQ * DOUT;
    encode<<<(total + 255) / 256, 256, 0, stream>>>(
        c_num, c_cat, x_num, x_cat, delta, u, cEnc, qEnc, g_logits);
    nca_main<<<dim3(NQ / QT, NCHUNK), 512, 0, stream>>>(
        cEnc, qEnc, c_y, g_logits, parts);
    finalize<<<(NQ + 255) / 256, 256, 0, stream>>>(g_logits, parts, (float*)d_out);
}

// Round 8
// 104.855 us; speedup vs baseline: 1.0693x; 1.0693x over previous
//
#include <hip/hip_runtime.h>
#include <math.h>

#define NQ 512
#define NC 8000
#define DNUM 6
#define NBINS 50
#define DCAT 20
#define DENC 26      // DNUM + DCAT
#define DOUT 10
#define CHUNK 1000
#define NCHUNK 8
#define QT 8         // queries per dist_k block
#define PSTRIDE 12   // per-(q,chunk) partial: 10 class sums, s, m

// ---------- encode ----------
// G_f(v) = sum_j ceil((v - u_fj*delta_fj)/delta_fj). Each per-bin map is
// fp-monotone in v (sub, div-by-positive, ceil), so all 50 bin diffs for a
// feature share sign => sum_j |bin_j(x)-bin_j(c)| == |G_f(x)-G_f(c)| exactly
// (integer-valued floats, sums << 2^24). 320-dim L1 -> 26-dim L1.
__global__ void encode(const float* __restrict__ c_num, const float* __restrict__ c_cat,
                       const float* __restrict__ x_num, const float* __restrict__ x_cat,
                       const float* __restrict__ delta, const float* __restrict__ u,
                       float* __restrict__ cEnc, float* __restrict__ qEnc) {
    int i = blockIdx.x * 256 + threadIdx.x;
    const int nA = (NC + NQ) * DNUM;          // 51072
    const int nB = (NC + NQ) * DCAT;          // 170240
    if (i < nA) {
        int f = i % DNUM, p = i / DNUM;
        bool is_c = p < NC;
        int idx = is_c ? p : p - NC;
        float v = (is_c ? c_num : x_num)[idx * DNUM + f];
        float g = 0.f;
        for (int j = 0; j < NBINS; ++j) {
            // exact reference op order: scaled_u = u*delta; ceil((v - scaled_u)/delta)
            float dl = delta[f * NBINS + j];
            float sc = u[f * NBINS + j] * dl;
            g += ceilf((v - sc) / dl);
        }
        if (is_c) cEnc[f * NC + idx] = g;
        else      qEnc[f * NQ + idx] = g;
    } else if (i < nA + nB) {
        int i2 = i - nA;
        int k = i2 % DCAT, p = i2 / DCAT;
        bool is_c = p < NC;
        int idx = is_c ? p : p - NC;
        float v = (is_c ? c_cat : x_cat)[idx * DCAT + k];
        if (is_c) cEnc[(DNUM + k) * NC + idx] = v;
        else      qEnc[(DNUM + k) * NQ + idx] = v;
    }
}

// ---------- A: pure compute — distance matrix D[q][c], no atomics/shuffles ----------
// grid (32 c-blocks, 64 q-tiles) = 2048 blocks x 256 thr = 8/CU, one round.
__global__ __launch_bounds__(256) void dist_k(
    const float* __restrict__ cEnc, const float* __restrict__ qEnc,
    float* __restrict__ D) {
    __shared__ float xs[DENC * QT];           // 208 floats
    const int tid = threadIdx.x;
    const int c = blockIdx.x * 256 + tid;
    const int q0 = blockIdx.y * QT;

    if (tid < DENC * QT) {
        int d = tid >> 3, q = tid & 7;
        xs[tid] = qEnc[d * NQ + q0 + q];
    }
    __syncthreads();

    const int cc = (c < NC) ? c : NC - 1;
    float cv[DENC];
#pragma unroll
    for (int d = 0; d < DENC; ++d) cv[d] = cEnc[(size_t)d * NC + cc];

    float acc[QT];
#pragma unroll
    for (int q = 0; q < QT; ++q) acc[q] = 0.f;
#pragma unroll
    for (int d = 0; d < DENC; ++d) {
        float cvd = cv[d];
        const float* xv = xs + d * QT;
#pragma unroll
        for (int q = 0; q < QT; ++q) acc[q] += fabsf(cvd - xv[q]);
    }
    if (c < NC) {
#pragma unroll
        for (int q = 0; q < QT; ++q) D[(size_t)(q0 + q) * NC + c] = acc[q];
    }
}

// ---------- B: pure reduction — one block per (q, chunk) ----------
// 250 active threads x float4 = 1000 dists (4 KB contiguous). Class sums in
// registers via predicated adds (no scatter, no atomics); one 11-value
// wave-tree reduce; block writes its 12-float partial. No global atomics.
__global__ __launch_bounds__(256) void reduce_k(
    const float* __restrict__ D, const int* __restrict__ cy,
    float* __restrict__ parts) {
    __shared__ float wr[4][12];
    __shared__ float m_sh;

    const int tid = threadIdx.x;
    const int chunk = blockIdx.x;
    const int q = blockIdx.y;
    const int lane = tid & 63, wave = tid >> 6;

    const bool act = (tid < CHUNK / 4);                // 250
    const int base = chunk * CHUNK + (act ? 4 * tid : CHUNK - 4);
    float4 dv = *(const float4*)(D + (size_t)q * NC + base);
    int4 yv = *(const int4*)(cy + base);

    // ---- chunk min(dist) ----
    float v = act ? fminf(fminf(dv.x, dv.y), fminf(dv.z, dv.w)) : INFINITY;
#pragma unroll
    for (int m = 32; m >= 1; m >>= 1) v = fminf(v, __shfl_xor(v, m));
    if (lane == 0) wr[wave][0] = v;
    __syncthreads();
    if (tid == 0)
        m_sh = fminf(fminf(wr[0][0], wr[1][0]), fminf(wr[2][0], wr[3][0]));
    __syncthreads();
    const float m = m_sh;

    // ---- partials: r[0..9] = class sums of exp(-d), r[10] = sum exp(m-d) ----
    float r[11];
#pragma unroll
    for (int k = 0; k < 11; ++k) r[k] = 0.f;
    if (act) {
        float e0 = __expf(-dv.x), e1 = __expf(-dv.y),
              e2 = __expf(-dv.z), e3 = __expf(-dv.w);
#pragma unroll
        for (int k = 0; k < DOUT; ++k) {
            r[k] = (yv.x == k ? e0 : 0.f) + (yv.y == k ? e1 : 0.f) +
                   (yv.z == k ? e2 : 0.f) + (yv.w == k ? e3 : 0.f);
        }
        r[10] = __expf(m - dv.x) + __expf(m - dv.y) +
                __expf(m - dv.z) + __expf(m - dv.w);
    }
#pragma unroll
    for (int k = 0; k < 11; ++k) {
        float s = r[k];
#pragma unroll
        for (int mm = 32; mm >= 1; mm >>= 1) s += __shfl_xor(s, mm);
        if (lane == 0) wr[wave][k] = s;
    }
    __syncthreads();
    if (tid < 11) {
        float s = wr[0][tid] + wr[1][tid] + wr[2][tid] + wr[3][tid];
        parts[((size_t)q * NCHUNK + chunk) * PSTRIDE + tid] = s;
    }
    if (tid == 11)
        parts[((size_t)q * NCHUNK + chunk) * PSTRIDE + 11] = m;
}

// ---------- finalize ----------
__global__ void finalize(const float* __restrict__ parts, float* __restrict__ out) {
    int q = blockIdx.x * 256 + threadIdx.x;
    if (q >= NQ) return;
    float logits[DOUT];
#pragma unroll
    for (int k = 0; k < DOUT; ++k) logits[k] = 0.f;
    float lse = 0.f;
#pragma unroll
    for (int ch = 0; ch < NCHUNK; ++ch) {
        const float* p = parts + ((size_t)q * NCHUNK + ch) * PSTRIDE;
#pragma unroll
        for (int k = 0; k < DOUT; ++k) logits[k] += p[k];
        lse += logf(p[10]) - p[11];       // log(sum exp(m-d)) - m
    }
#pragma unroll
    for (int k = 0; k < DOUT; ++k)
        out[q * DOUT + k] = logf(logits[k] + 1e-8f) - lse;
}

extern "C" void kernel_launch(void* const* d_in, const int* in_sizes, int n_in,
                              void* d_out, int out_size, void* d_ws, size_t ws_size,
                              hipStream_t stream) {
    const float* x_num = (const float*)d_in[0];
    const float* x_cat = (const float*)d_in[1];
    const float* c_num = (const float*)d_in[2];
    const float* c_cat = (const float*)d_in[3];
    const int*   c_y   = (const int*)d_in[4];
    const float* delta = (const float*)d_in[5];
    const float* u     = (const float*)d_in[6];

    float* ws = (float*)d_ws;
    float* cEnc = ws;                             // 26*8000 = 208,000 floats
    float* qEnc = cEnc + (size_t)DENC * NC;       // 26*512  = 13,312
    float* Dmat = qEnc + (size_t)DENC * NQ;       // 512*8000 = 4,096,000
    float* parts = Dmat + (size_t)NQ * NC;        // 512*8*12 = 49,152

    const int total = (NC + NQ) * DENC;
    encode<<<(total + 255) / 256, 256, 0, stream>>>(
        c_num, c_cat, x_num, x_cat, delta, u, cEnc, qEnc);
    dist_k<<<dim3((NC + 255) / 256, NQ / QT), 256, 0, stream>>>(cEnc, qEnc, Dmat);
    reduce_k<<<dim3(NCHUNK, NQ), 256, 0, stream>>>(Dmat, c_y, parts);
    finalize<<<(NQ + 255) / 256, 256, 0, stream>>>(parts, (float*)d_out);
}